// Round 6
// baseline (433.177 us; speedup 1.0000x reference)
//
#include <hip/hip_runtime.h>
#include <hip/hip_bf16.h>
#include <math.h>

#define NND 50000
#define NE 800000
#define NF 128
#define NH 64
#define NB 512
#define KP 30
#define NCLS 10

typedef __hip_bfloat16 bf16;

__device__ __forceinline__ float ldF(const void* p, size_t i, int isbf){
    return isbf ? __bfloat162float(((const bf16*)p)[i]) : ((const float*)p)[i];
}

// ---------------- dtype probe: flags[0]=floats-are-bf16, flags[1]=ints-are-int64 ----
__global__ void probe_kernel(const unsigned int* __restrict__ xw,
                             const int* __restrict__ ew, int* __restrict__ flags){
    __shared__ int cF, cI;
    if (threadIdx.x == 0){ cF = 0; cI = 0; }
    __syncthreads();
    unsigned int w = xw[threadIdx.x];
    int ex = (int)((w >> 7) & 0xFF);
    if (ex >= 100 && ex <= 140) atomicAdd(&cF, 1);
    if (ew[2*threadIdx.x + 1] == 0) atomicAdd(&cI, 1);
    __syncthreads();
    if (threadIdx.x == 0){
        flags[0] = (cF >= 128) ? 1 : 0;
        flags[1] = (cI >= 192) ? 1 : 0;
    }
}

__device__ __forceinline__ int edgeSrc(const int* ei, int e, int i64){
    return i64 ? ei[2*e] : ei[e];
}
__device__ __forceinline__ int edgeDst(const int* ei, int e, int i64){
    return i64 ? ei[2*NE + 2*e] : ei[NE + e];
}

// ------------- setup: per-graph starts + fp32 head-weight preconvert (merged) ------
__global__ __launch_bounds__(256) void setup_kernel(
    const int* __restrict__ batch, int* __restrict__ starts,
    const void* __restrict__ convw, const void* __restrict__ convb,
    const void* __restrict__ l1w, const void* __restrict__ l1b,
    const void* __restrict__ l2w, const void* __restrict__ l2b,
    float* __restrict__ wT, float* __restrict__ cbf,
    float* __restrict__ l1wf, float* __restrict__ l1bf,
    float* __restrict__ l2wf, float* __restrict__ l2bf,
    const int* __restrict__ flags)
{
    int wbf = flags[0];
    int i64 = flags[1];
    int i = blockIdx.x*256 + threadIdx.x;
    if (i < NND){
        int b  = i64 ? batch[2*i] : batch[i];
        int pb = (i == 0) ? -1 : (i64 ? batch[2*(i-1)] : batch[i-1]);
        for (int g = pb+1; g <= b; ++g) starts[g] = i;
        if (i == NND-1) for (int g = b+1; g <= NB; ++g) starts[g] = NND;
    }
    if (i < 10240){
        int o = i / 320, rem = i - o*320, ch = rem/5, h = rem - ch*5;
        wT[ch*160 + h*32 + o] = ldF(convw, i, wbf);   // wT[ch][h][o]
    }
    if (i < 53248) l1wf[i] = ldF(l1w, i, wbf);
    if (i < 640)   l2wf[i] = ldF(l2w, i, wbf);
    if (i < 64)    l1bf[i] = ldF(l1b, i, wbf);
    if (i < 32)    cbf[i]  = ldF(convb, i, wbf);
    if (i < 10)    l2bf[i] = ldF(l2b, i, wbf);
}

// ---------------- CSR build ----------------
__global__ __launch_bounds__(256) void count_kernel(const int* __restrict__ ei,
                                                    int* __restrict__ cnt,
                                                    const int* __restrict__ flags){
    int e = blockIdx.x*256 + threadIdx.x;
    if (e >= NE) return;
    atomicAdd(&cnt[edgeDst(ei, e, flags[1])], 1);
}

__global__ __launch_bounds__(1024) void scan1_kernel(const int* __restrict__ cnt,
                                                     int* __restrict__ offs,
                                                     int* __restrict__ bsum){
    __shared__ int buf[1024];
    int tid = threadIdx.x;
    int i = blockIdx.x*1024 + tid;
    int v = (i < NND) ? cnt[i] : 0;
    buf[tid] = v;
    __syncthreads();
    for (int st = 1; st < 1024; st <<= 1){
        int t = (tid >= st) ? buf[tid-st] : 0;
        __syncthreads();
        buf[tid] += t;
        __syncthreads();
    }
    if (i < NND) offs[i] = buf[tid] - v;
    if (tid == 1023) bsum[blockIdx.x] = buf[1023];
}

// scan3 also does the (tiny) block-sum prefix locally — no scan2 kernel needed
__global__ __launch_bounds__(256) void scan3_kernel(int* __restrict__ offs,
                                                    const int* __restrict__ bsum,
                                                    int nb){
    __shared__ int bs[64];
    int tid = threadIdx.x;
    if (tid < nb) bs[tid] = bsum[tid];
    __syncthreads();
    if (tid == 0){
        int acc = 0;
        for (int b = 0; b < nb; ++b){ int t = bs[b]; bs[b] = acc; acc += t; }
    }
    __syncthreads();
    int i = blockIdx.x*256 + tid;
    if (i < NND) offs[i] += bs[i >> 10];
    if (i == 0) offs[NND] = NE;
}

// csr write via atomicExch: atomics resolve past L2 at op granularity ->
// avoids the 64B/edge partial-line writeback amplification of plain scattered stores
__global__ __launch_bounds__(256) void fill_kernel(const int* __restrict__ ei,
                                                   const int* __restrict__ offs,
                                                   int* __restrict__ cur,
                                                   int* __restrict__ csr,
                                                   const int* __restrict__ flags){
    int e = blockIdx.x*256 + threadIdx.x;
    if (e >= NE) return;
    int i64 = flags[1];
    int d = edgeDst(ei, e, i64);
    int p = atomicAdd(&cur[d], 1);
    atomicExch(&csr[offs[d] + p], edgeSrc(ei, e, i64));
}

// ---------------- dual GEMM: y = h@Wl ; z = h@Wr + b ----------------
template<int K, typename TW>
__device__ __forceinline__ void dual_loop(const TW* __restrict__ Wl, const TW* __restrict__ Wr,
                                          const float* r0, const float* r1,
                                          const float* r2, const float* r3,
                                          int f, float* ay, float* az){
    #pragma unroll 4
    for (int k = 0; k < K; ++k){
        float wl = (float)Wl[(size_t)k*NH + f];
        float wr = (float)Wr[(size_t)k*NH + f];
        float v0 = r0[k], v1 = r1[k], v2 = r2[k], v3 = r3[k];
        ay[0] += wl*v0; ay[1] += wl*v1; ay[2] += wl*v2; ay[3] += wl*v3;
        az[0] += wr*v0; az[1] += wr*v1; az[2] += wr*v2; az[3] += wr*v3;
    }
}

template<int K>
__global__ __launch_bounds__(256) void dualgemm_kernel(
    const void* __restrict__ in, const void* __restrict__ Wl_,
    const void* __restrict__ Wr_, const void* __restrict__ bias,
    float* __restrict__ y, float* __restrict__ z,
    const int* __restrict__ flags, int inIsF32)
{
    __shared__ float inR[16*K];
    int isbf = inIsF32 ? 0 : flags[0];
    int wbf  = flags[0];
    int tid = threadIdx.x;
    int base = blockIdx.x * 16;
    for (int i = tid; i < 16*K; i += 256){
        int r = i / K, c = i - r*K;
        int node = base + r;
        inR[i] = (node < NND) ? ldF(in, (size_t)node*K + c, isbf) : 0.f;
    }
    __syncthreads();
    int f = tid & 63, ng = tid >> 6;
    float ay[4] = {0,0,0,0}, az[4] = {0,0,0,0};
    const float* r0 = &inR[(ng*4+0)*K];
    const float* r1 = &inR[(ng*4+1)*K];
    const float* r2 = &inR[(ng*4+2)*K];
    const float* r3 = &inR[(ng*4+3)*K];
    if (wbf) dual_loop<K>((const bf16*)Wl_, (const bf16*)Wr_, r0,r1,r2,r3, f, ay, az);
    else     dual_loop<K>((const float*)Wl_,(const float*)Wr_, r0,r1,r2,r3, f, ay, az);
    float bv = ldF(bias, f, wbf);
    #pragma unroll
    for (int j = 0; j < 4; ++j){
        int node = base + ng*4 + j;
        if (node < NND){
            y[(size_t)node*NH + f] = ay[j];
            z[(size_t)node*NH + f] = az[j] + bv;
        }
    }
}

// ---------------- pure gather: out = relu( mean_csr(y) + z ), float4 ------
__global__ __launch_bounds__(256) void gather_kernel(
    const float4* __restrict__ y4, const int* __restrict__ offs,
    const int* __restrict__ csr, const float* __restrict__ z,
    float* __restrict__ out)
{
    int t = blockIdx.x*256 + threadIdx.x;
    int node = t >> 4;
    int q = t & 15;
    if (node >= NND) return;
    int o0 = offs[node], o1 = offs[node+1];
    float ax=0.f, ayv=0.f, azv=0.f, aw=0.f;
    int e = o0;
    for (; e + 3 < o1; e += 4){
        int s0 = csr[e], s1 = csr[e+1], s2 = csr[e+2], s3 = csr[e+3];
        float4 a = y4[(size_t)s0*16 + q];
        float4 b = y4[(size_t)s1*16 + q];
        float4 c = y4[(size_t)s2*16 + q];
        float4 d = y4[(size_t)s3*16 + q];
        ax  += a.x + b.x + c.x + d.x;
        ayv += a.y + b.y + c.y + d.y;
        azv += a.z + b.z + c.z + d.z;
        aw  += a.w + b.w + c.w + d.w;
    }
    for (; e < o1; ++e){
        float4 a = y4[(size_t)csr[e]*16 + q];
        ax += a.x; ayv += a.y; azv += a.z; aw += a.w;
    }
    float dd = (float)(o1 - o0); dd = dd > 1.f ? dd : 1.f;
    float inv = 1.f / dd;
    size_t base = (size_t)node*NH + q*4;
    float4 zz = *(const float4*)&z[base];
    float4 v;
    v.x = ax *inv + zz.x; v.y = ayv*inv + zz.y;
    v.z = azv*inv + zz.z; v.w = aw *inv + zz.w;
    v.x = v.x > 0.f ? v.x : 0.f;  v.y = v.y > 0.f ? v.y : 0.f;
    v.z = v.z > 0.f ? v.z : 0.f;  v.w = v.w > 0.f ? v.w : 0.f;
    *(float4*)&out[base] = v;
}

// ------ fused head: wave0 top-30 selection -> LDS; conv + fc1 + fc2 + log_softmax ----
__global__ __launch_bounds__(256) void head2_kernel(
    const float* __restrict__ h3, const int* __restrict__ starts,
    const float* __restrict__ wT, const float* __restrict__ cbf,
    const float* __restrict__ l1wf, const float* __restrict__ l1bf,
    const float* __restrict__ l2wf, const float* __restrict__ l2bf,
    float* __restrict__ outp)
{
    __shared__ float pT[64*32];          // pT[ch][rank], ranks 30,31 zeroed
    __shared__ float part[8*832];
    __shared__ float cbuf[832];
    __shared__ float fbuf[NH];
    __shared__ float logitsS[NCLS];
    int g = blockIdx.x, tid = threadIdx.x;
    int s = starts[g], e = starts[g+1];

    if (tid < 64){
        int lane = tid;
        int cnt = e - s; if (cnt > 256) cnt = 256; if (cnt < 0) cnt = 0;
        float k0 = (lane       < cnt) ? h3[(size_t)(s+lane      )*NH + 63] : -1e30f;
        float k1 = (lane + 64  < cnt) ? h3[(size_t)(s+lane +  64)*NH + 63] : -1e30f;
        float k2 = (lane + 128 < cnt) ? h3[(size_t)(s+lane + 128)*NH + 63] : -1e30f;
        float k3 = (lane + 192 < cnt) ? h3[(size_t)(s+lane + 192)*NH + 63] : -1e30f;
        #pragma unroll
        for (int r = 0; r < KP; ++r){
            float bv = k0; int bi = lane;
            if (k1 > bv){ bv = k1; bi = lane + 64;  }
            if (k2 > bv){ bv = k2; bi = lane + 128; }
            if (k3 > bv){ bv = k3; bi = lane + 192; }
            #pragma unroll
            for (int st = 32; st > 0; st >>= 1){
                float ov = __shfl_xor(bv, st, 64);
                int   oi = __shfl_xor(bi, st, 64);
                if (ov > bv || (ov == bv && oi < bi)){ bv = ov; bi = oi; }
            }
            float v = 0.f;
            if (bv > -1e29f){
                v = h3[(size_t)(s+bi)*NH + lane];       // coalesced row read
                if      (bi == lane      ) k0 = -1e30f;
                else if (bi == lane + 64 ) k1 = -1e30f;
                else if (bi == lane + 128) k2 = -1e30f;
                else if (bi == lane + 192) k3 = -1e30f;
            }
            pT[lane*32 + r] = v;
        }
        pT[lane*32 + 30] = 0.f;
        pT[lane*32 + 31] = 0.f;
    }
    __syncthreads();

    int o = tid & 31, chg = tid >> 5;
    float acc[26];
    #pragma unroll
    for (int t = 0; t < 26; ++t) acc[t] = 0.f;
    for (int c8 = 0; c8 < 8; ++c8){
        int ch = chg*8 + c8;
        const float4* prow = (const float4*)&pT[ch*32];
        float p[32];
        #pragma unroll
        for (int q = 0; q < 8; ++q){
            float4 v = prow[q];
            p[4*q]=v.x; p[4*q+1]=v.y; p[4*q+2]=v.z; p[4*q+3]=v.w;
        }
        const float* wrow = &wT[ch*160 + o];
        #pragma unroll
        for (int h = 0; h < 5; ++h){
            float wv = wrow[h*32];                  // coalesced across o-lanes
            #pragma unroll
            for (int t = 0; t < 26; ++t) acc[t] += p[t+h]*wv;
        }
    }
    #pragma unroll
    for (int t = 0; t < 26; ++t) part[chg*832 + o*26 + t] = acc[t];
    __syncthreads();

    for (int i = tid; i < 832; i += 256){
        int oo = i / 26;
        float a = cbf[oo];
        #pragma unroll
        for (int cg = 0; cg < 8; ++cg) a += part[cg*832 + i];
        cbuf[i] = a > 0.f ? a : 0.f;
    }
    __syncthreads();

    {   // fc1: 832 -> 64, 4 partial groups
        int p = tid >> 6, j = tid & 63;
        float a = 0.f;
        int m0 = p*208;
        #pragma unroll 4
        for (int m = m0; m < m0 + 208; ++m)
            a += cbuf[m] * l1wf[(size_t)m*NH + j];
        part[p*NH + j] = a;
    }
    __syncthreads();
    if (tid < NH){
        float v = part[tid] + part[NH+tid] + part[2*NH+tid] + part[3*NH+tid] + l1bf[tid];
        fbuf[tid] = v > 0.f ? v : 0.f;
    }
    __syncthreads();
    if (tid < NCLS){
        float a = l2bf[tid];
        #pragma unroll
        for (int j = 0; j < NH; ++j) a += fbuf[j] * l2wf[j*NCLS + tid];
        logitsS[tid] = a;
    }
    __syncthreads();
    if (tid == 0){
        float m = logitsS[0];
        for (int c = 1; c < NCLS; ++c) m = fmaxf(m, logitsS[c]);
        float ssum = 0.f;
        for (int c = 0; c < NCLS; ++c) ssum += expf(logitsS[c]-m);
        float lse = m + logf(ssum);
        for (int c = 0; c < NCLS; ++c)
            outp[(size_t)g*NCLS + c] = logitsS[c] - lse;
    }
}

extern "C" void kernel_launch(void* const* d_in, const int* in_sizes, int n_in,
                              void* d_out, int out_size, void* d_ws, size_t ws_size,
                              hipStream_t stream) {
    const void* x    = d_in[0];
    const int*  ei   = (const int*)d_in[1];
    const int*  batch= (const int*)d_in[2];
    const void *W1l=d_in[3], *b1=d_in[4],  *W1r=d_in[5];
    const void *W2l=d_in[6], *b2=d_in[7],  *W2r=d_in[8];
    const void *W3l=d_in[9], *b3=d_in[10], *W3r=d_in[11];
    const void *convw=d_in[12], *convb=d_in[13];
    const void *l1w=d_in[14], *l1b=d_in[15];
    const void *l2w=d_in[16], *l2b=d_in[17];
    float* out = (float*)d_out;

    float* wsf = (float*)d_ws;
    float* A  = wsf;                             // 50000*64
    float* Bb = A  + (size_t)NND*NH;             // 50000*64
    float* C  = Bb + (size_t)NND*NH;             // 50000*64
    float* wT   = C + (size_t)NND*NH;            // 10240
    float* cbf  = wT + 10240;                    // 32
    float* l1wf = cbf + 32;                      // 53248
    float* l1bf = l1wf + 53248;                  // 64
    float* l2wf = l1bf + 64;                     // 640
    float* l2bf = l2wf + 640;                    // 10 (+pad)
    int* starts = (int*)(l2bf + 16);             // 513
    int* flags  = starts + 520;                  // 2
    int* cnt    = flags + 8;                     // 50000
    int* offs   = cnt + NND;                     // 50001
    int* cur    = offs + NND + 3;                // 50000
    int* bsum   = cur + NND;                     // 64
    int* csr    = bsum + 64;                     // 800000

    const int NBLK = (NND + 1023)/1024;          // 49

    probe_kernel<<<1, 256, 0, stream>>>((const unsigned int*)x, ei, flags);
    setup_kernel<<<(53248+255)/256, 256, 0, stream>>>(batch, starts,
                                                      convw, convb, l1w, l1b, l2w, l2b,
                                                      wT, cbf, l1wf, l1bf, l2wf, l2bf, flags);

    // ---- CSR build (once) ----
    hipMemsetAsync(cnt, 0, NND*sizeof(int), stream);
    hipMemsetAsync(cur, 0, NND*sizeof(int), stream);
    count_kernel<<<(NE+255)/256, 256, 0, stream>>>(ei, cnt, flags);
    scan1_kernel<<<NBLK, 1024, 0, stream>>>(cnt, offs, bsum);
    scan3_kernel<<<(NND+255)/256, 256, 0, stream>>>(offs, bsum, NBLK);
    fill_kernel<<<(NE+255)/256, 256, 0, stream>>>(ei, offs, cur, csr, flags);

    int gblocks = (NND + 15)/16;                 // 3125
    int ngath   = (NND*16 + 255)/256;            // 3125

    // ---- layer 1: x -> B ----
    dualgemm_kernel<NF><<<gblocks,256,0,stream>>>(x, W1l, W1r, b1, A, Bb, flags, 0);
    gather_kernel<<<ngath,256,0,stream>>>((const float4*)A, offs, csr, Bb, Bb);

    // ---- layer 2: B -> C ----
    dualgemm_kernel<NH><<<gblocks,256,0,stream>>>(Bb, W2l, W2r, b2, A, C, flags, 1);
    gather_kernel<<<ngath,256,0,stream>>>((const float4*)A, offs, csr, C, C);

    // ---- layer 3: C -> B ----
    dualgemm_kernel<NH><<<gblocks,256,0,stream>>>(C, W3l, W3r, b3, A, Bb, flags, 1);
    gather_kernel<<<ngath,256,0,stream>>>((const float4*)A, offs, csr, Bb, Bb);

    // ---- head: fused selection + dense tail ----
    head2_kernel<<<NB,256,0,stream>>>(Bb, starts, wT, cbf, l1wf, l1bf, l2wf, l2bf, out);
}

// Round 7
// 364.476 us; speedup vs baseline: 1.1885x; 1.1885x over previous
//
#include <hip/hip_runtime.h>
#include <hip/hip_bf16.h>
#include <math.h>

#define NND 50000
#define NE 800000
#define NF 128
#define NH 64
#define NB 512
#define KP 30
#define NCLS 10
#define NBKT 49              // coarse buckets of 1024 dsts: (50000+1023)>>10

typedef __hip_bfloat16 bf16;

__device__ __forceinline__ float ldF(const void* p, size_t i, int isbf){
    return isbf ? __bfloat162float(((const bf16*)p)[i]) : ((const float*)p)[i];
}

// ---------------- dtype probe: flags[0]=floats-are-bf16, flags[1]=ints-are-int64 ----
__global__ void probe_kernel(const unsigned int* __restrict__ xw,
                             const int* __restrict__ ew, int* __restrict__ flags){
    __shared__ int cF, cI;
    if (threadIdx.x == 0){ cF = 0; cI = 0; }
    __syncthreads();
    unsigned int w = xw[threadIdx.x];
    int ex = (int)((w >> 7) & 0xFF);
    if (ex >= 100 && ex <= 140) atomicAdd(&cF, 1);
    if (ew[2*threadIdx.x + 1] == 0) atomicAdd(&cI, 1);
    __syncthreads();
    if (threadIdx.x == 0){
        flags[0] = (cF >= 128) ? 1 : 0;
        flags[1] = (cI >= 192) ? 1 : 0;
    }
}

__device__ __forceinline__ int edgeSrc(const int* ei, int e, int i64){
    return i64 ? ei[2*e] : ei[e];
}
__device__ __forceinline__ int edgeDst(const int* ei, int e, int i64){
    return i64 ? ei[2*NE + 2*e] : ei[NE + e];
}

// ------------- setup: per-graph starts + fp32 head-weight preconvert (merged) ------
__global__ __launch_bounds__(256) void setup_kernel(
    const int* __restrict__ batch, int* __restrict__ starts,
    const void* __restrict__ convw, const void* __restrict__ convb,
    const void* __restrict__ l1w, const void* __restrict__ l1b,
    const void* __restrict__ l2w, const void* __restrict__ l2b,
    float* __restrict__ wT, float* __restrict__ cbf,
    float* __restrict__ l1wf, float* __restrict__ l1bf,
    float* __restrict__ l2wf, float* __restrict__ l2bf,
    const int* __restrict__ flags)
{
    int wbf = flags[0];
    int i64 = flags[1];
    int i = blockIdx.x*256 + threadIdx.x;
    if (i < NND){
        int b  = i64 ? batch[2*i] : batch[i];
        int pb = (i == 0) ? -1 : (i64 ? batch[2*(i-1)] : batch[i-1]);
        for (int g = pb+1; g <= b; ++g) starts[g] = i;
        if (i == NND-1) for (int g = b+1; g <= NB; ++g) starts[g] = NND;
    }
    if (i < 10240){
        int o = i / 320, rem = i - o*320, ch = rem/5, h = rem - ch*5;
        wT[ch*160 + h*32 + o] = ldF(convw, i, wbf);   // wT[ch][h][o]
    }
    if (i < 53248) l1wf[i] = ldF(l1w, i, wbf);
    if (i < 640)   l2wf[i] = ldF(l2w, i, wbf);
    if (i < 64)    l1bf[i] = ldF(l1b, i, wbf);
    if (i < 32)    cbf[i]  = ldF(convb, i, wbf);
    if (i < 10)    l2bf[i] = ldF(l2b, i, wbf);
}

// ============ CSR build via 2-level bucket sort (no random 4B global scatter) =====
// Lesson R6: scattered 4B stores/atomics pay ~64B/line partial-writeback (~50MB, 70us).
// Fix: confine final placement to a ~65KB per-block window so lines fill in one L2.

// (1) coarse histogram: bucket = dst>>10
__global__ __launch_bounds__(256) void bucket_count(const int* __restrict__ ei,
                                                    int* __restrict__ bcnt,
                                                    const int* __restrict__ flags){
    __shared__ int lh[NBKT];
    int tid = threadIdx.x;
    int i64 = flags[1];
    if (tid < NBKT) lh[tid] = 0;
    __syncthreads();
    int t0 = blockIdx.x*4096;
    #pragma unroll 4
    for (int k = 0; k < 16; ++k){
        int e = t0 + k*256 + tid;
        if (e < NE) atomicAdd(&lh[edgeDst(ei,e,i64) >> 10], 1);
    }
    __syncthreads();
    if (tid < NBKT && lh[tid]) atomicAdd(&bcnt[tid], lh[tid]);
}

// (2) tiny scan: bbase = exclusive prefix of bcnt; bcur = bbase; offs[NND]=NE
__global__ void bucket_scan(const int* __restrict__ bcnt, int* __restrict__ bbase,
                            int* __restrict__ bcur, int* __restrict__ offs){
    if (threadIdx.x == 0){
        int acc = 0;
        for (int b = 0; b < NBKT; ++b){
            bbase[b] = acc; bcur[b] = acc; acc += bcnt[b];
        }
        bbase[NBKT] = acc;
        offs[NND] = NE;
    }
}

// (3) scatter edges into coarse buckets as int2(src,dst) — runs of ~84 edges/bucket/tile
__global__ __launch_bounds__(256) void bucket_scatter(const int* __restrict__ ei,
                                                      int* __restrict__ bcur,
                                                      int2* __restrict__ bedges,
                                                      const int* __restrict__ flags){
    __shared__ int lh[NBKT];
    __shared__ int lcur[NBKT];
    int tid = threadIdx.x;
    int i64 = flags[1];
    if (tid < NBKT) lh[tid] = 0;
    __syncthreads();
    int t0 = blockIdx.x*4096;
    int myd[16], mys[16];
    int cnt = 0;
    #pragma unroll 4
    for (int k = 0; k < 16; ++k){
        int e = t0 + k*256 + tid;
        if (e < NE){
            int d = edgeDst(ei,e,i64), s_ = edgeSrc(ei,e,i64);
            myd[cnt] = d; mys[cnt] = s_; ++cnt;
            atomicAdd(&lh[d >> 10], 1);
        }
    }
    __syncthreads();
    if (tid < NBKT) lcur[tid] = lh[tid] ? atomicAdd(&bcur[tid], lh[tid]) : 0;
    __syncthreads();
    for (int k = 0; k < cnt; ++k){
        int b = myd[k] >> 10;
        int p = atomicAdd(&lcur[b], 1);
        bedges[p] = make_int2(mys[k], myd[k]);
    }
}

// (4) per-bucket fine CSR: LDS hist+scan over 1024 local dsts; writes offs coalesced
//     and csr into a contiguous [bbase[b], bbase[b+1]) window (single-L2 resident)
__global__ __launch_bounds__(1024) void csr_finalize(const int2* __restrict__ bedges,
                                                     const int* __restrict__ bbase,
                                                     int* __restrict__ offs,
                                                     int* __restrict__ csr){
    __shared__ int hist[1024];
    int b = blockIdx.x;
    int tid = threadIdx.x;
    int dst0 = b << 10;
    int nd = NND - dst0; if (nd > 1024) nd = 1024;
    int e0 = bbase[b], e1 = bbase[b+1];
    hist[tid] = 0;
    __syncthreads();
    for (int e = e0 + tid; e < e1; e += 1024)
        atomicAdd(&hist[bedges[e].y - dst0], 1);
    __syncthreads();
    int own = hist[tid];
    // in-place Hillis-Steele inclusive scan
    for (int st = 1; st < 1024; st <<= 1){
        int v = (tid >= st) ? hist[tid-st] : 0;
        __syncthreads();
        hist[tid] += v;
        __syncthreads();
    }
    int excl = hist[tid] - own;
    if (tid < nd) offs[dst0 + tid] = e0 + excl;
    __syncthreads();
    hist[tid] = excl;                 // becomes the per-dst cursor
    __syncthreads();
    for (int e = e0 + tid; e < e1; e += 1024){
        int2 ed = bedges[e];
        int p = atomicAdd(&hist[ed.y - dst0], 1);   // LDS atomic
        csr[e0 + p] = ed.x;           // confined ~65KB window per block
    }
}

// ---------------- dual GEMM: y = h@Wl ; z = h@Wr + b ----------------
template<int K, typename TW>
__device__ __forceinline__ void dual_loop(const TW* __restrict__ Wl, const TW* __restrict__ Wr,
                                          const float* r0, const float* r1,
                                          const float* r2, const float* r3,
                                          int f, float* ay, float* az){
    #pragma unroll 4
    for (int k = 0; k < K; ++k){
        float wl = (float)Wl[(size_t)k*NH + f];
        float wr = (float)Wr[(size_t)k*NH + f];
        float v0 = r0[k], v1 = r1[k], v2 = r2[k], v3 = r3[k];
        ay[0] += wl*v0; ay[1] += wl*v1; ay[2] += wl*v2; ay[3] += wl*v3;
        az[0] += wr*v0; az[1] += wr*v1; az[2] += wr*v2; az[3] += wr*v3;
    }
}

template<int K>
__global__ __launch_bounds__(256) void dualgemm_kernel(
    const void* __restrict__ in, const void* __restrict__ Wl_,
    const void* __restrict__ Wr_, const void* __restrict__ bias,
    float* __restrict__ y, float* __restrict__ z,
    const int* __restrict__ flags, int inIsF32)
{
    __shared__ float inR[16*K];
    int isbf = inIsF32 ? 0 : flags[0];
    int wbf  = flags[0];
    int tid = threadIdx.x;
    int base = blockIdx.x * 16;
    for (int i = tid; i < 16*K; i += 256){
        int r = i / K, c = i - r*K;
        int node = base + r;
        inR[i] = (node < NND) ? ldF(in, (size_t)node*K + c, isbf) : 0.f;
    }
    __syncthreads();
    int f = tid & 63, ng = tid >> 6;
    float ay[4] = {0,0,0,0}, az[4] = {0,0,0,0};
    const float* r0 = &inR[(ng*4+0)*K];
    const float* r1 = &inR[(ng*4+1)*K];
    const float* r2 = &inR[(ng*4+2)*K];
    const float* r3 = &inR[(ng*4+3)*K];
    if (wbf) dual_loop<K>((const bf16*)Wl_, (const bf16*)Wr_, r0,r1,r2,r3, f, ay, az);
    else     dual_loop<K>((const float*)Wl_,(const float*)Wr_, r0,r1,r2,r3, f, ay, az);
    float bv = ldF(bias, f, wbf);
    #pragma unroll
    for (int j = 0; j < 4; ++j){
        int node = base + ng*4 + j;
        if (node < NND){
            y[(size_t)node*NH + f] = ay[j];
            z[(size_t)node*NH + f] = az[j] + bv;
        }
    }
}

// ---------------- pure gather: out = relu( mean_csr(y) + z ), float4 ------
__global__ __launch_bounds__(256) void gather_kernel(
    const float4* __restrict__ y4, const int* __restrict__ offs,
    const int* __restrict__ csr, const float* __restrict__ z,
    float* __restrict__ out)
{
    int t = blockIdx.x*256 + threadIdx.x;
    int node = t >> 4;
    int q = t & 15;
    if (node >= NND) return;
    int o0 = offs[node], o1 = offs[node+1];
    float ax=0.f, ayv=0.f, azv=0.f, aw=0.f;
    int e = o0;
    for (; e + 3 < o1; e += 4){
        int s0 = csr[e], s1 = csr[e+1], s2 = csr[e+2], s3 = csr[e+3];
        float4 a = y4[(size_t)s0*16 + q];
        float4 b = y4[(size_t)s1*16 + q];
        float4 c = y4[(size_t)s2*16 + q];
        float4 d = y4[(size_t)s3*16 + q];
        ax  += a.x + b.x + c.x + d.x;
        ayv += a.y + b.y + c.y + d.y;
        azv += a.z + b.z + c.z + d.z;
        aw  += a.w + b.w + c.w + d.w;
    }
    for (; e < o1; ++e){
        float4 a = y4[(size_t)csr[e]*16 + q];
        ax += a.x; ayv += a.y; azv += a.z; aw += a.w;
    }
    float dd = (float)(o1 - o0); dd = dd > 1.f ? dd : 1.f;
    float inv = 1.f / dd;
    size_t base = (size_t)node*NH + q*4;
    float4 zz = *(const float4*)&z[base];
    float4 v;
    v.x = ax *inv + zz.x; v.y = ayv*inv + zz.y;
    v.z = azv*inv + zz.z; v.w = aw *inv + zz.w;
    v.x = v.x > 0.f ? v.x : 0.f;  v.y = v.y > 0.f ? v.y : 0.f;
    v.z = v.z > 0.f ? v.z : 0.f;  v.w = v.w > 0.f ? v.w : 0.f;
    *(float4*)&out[base] = v;
}

// ------ fused head: wave0 top-30 selection -> LDS; conv + fc1 + fc2 + log_softmax ----
__global__ __launch_bounds__(256) void head2_kernel(
    const float* __restrict__ h3, const int* __restrict__ starts,
    const float* __restrict__ wT, const float* __restrict__ cbf,
    const float* __restrict__ l1wf, const float* __restrict__ l1bf,
    const float* __restrict__ l2wf, const float* __restrict__ l2bf,
    float* __restrict__ outp)
{
    __shared__ float pT[64*32];          // pT[ch][rank], ranks 30,31 zeroed
    __shared__ float part[8*832];
    __shared__ float cbuf[832];
    __shared__ float fbuf[NH];
    __shared__ float logitsS[NCLS];
    int g = blockIdx.x, tid = threadIdx.x;
    int s = starts[g], e = starts[g+1];

    if (tid < 64){
        int lane = tid;
        int cnt = e - s; if (cnt > 256) cnt = 256; if (cnt < 0) cnt = 0;
        float k0 = (lane       < cnt) ? h3[(size_t)(s+lane      )*NH + 63] : -1e30f;
        float k1 = (lane + 64  < cnt) ? h3[(size_t)(s+lane +  64)*NH + 63] : -1e30f;
        float k2 = (lane + 128 < cnt) ? h3[(size_t)(s+lane + 128)*NH + 63] : -1e30f;
        float k3 = (lane + 192 < cnt) ? h3[(size_t)(s+lane + 192)*NH + 63] : -1e30f;
        #pragma unroll
        for (int r = 0; r < KP; ++r){
            float bv = k0; int bi = lane;
            if (k1 > bv){ bv = k1; bi = lane + 64;  }
            if (k2 > bv){ bv = k2; bi = lane + 128; }
            if (k3 > bv){ bv = k3; bi = lane + 192; }
            #pragma unroll
            for (int st = 32; st > 0; st >>= 1){
                float ov = __shfl_xor(bv, st, 64);
                int   oi = __shfl_xor(bi, st, 64);
                if (ov > bv || (ov == bv && oi < bi)){ bv = ov; bi = oi; }
            }
            float v = 0.f;
            if (bv > -1e29f){
                v = h3[(size_t)(s+bi)*NH + lane];       // coalesced row read
                if      (bi == lane      ) k0 = -1e30f;
                else if (bi == lane + 64 ) k1 = -1e30f;
                else if (bi == lane + 128) k2 = -1e30f;
                else if (bi == lane + 192) k3 = -1e30f;
            }
            pT[lane*32 + r] = v;
        }
        pT[lane*32 + 30] = 0.f;
        pT[lane*32 + 31] = 0.f;
    }
    __syncthreads();

    int o = tid & 31, chg = tid >> 5;
    float acc[26];
    #pragma unroll
    for (int t = 0; t < 26; ++t) acc[t] = 0.f;
    for (int c8 = 0; c8 < 8; ++c8){
        int ch = chg*8 + c8;
        const float4* prow = (const float4*)&pT[ch*32];
        float p[32];
        #pragma unroll
        for (int q = 0; q < 8; ++q){
            float4 v = prow[q];
            p[4*q]=v.x; p[4*q+1]=v.y; p[4*q+2]=v.z; p[4*q+3]=v.w;
        }
        const float* wrow = &wT[ch*160 + o];
        #pragma unroll
        for (int h = 0; h < 5; ++h){
            float wv = wrow[h*32];                  // coalesced across o-lanes
            #pragma unroll
            for (int t = 0; t < 26; ++t) acc[t] += p[t+h]*wv;
        }
    }
    #pragma unroll
    for (int t = 0; t < 26; ++t) part[chg*832 + o*26 + t] = acc[t];
    __syncthreads();

    for (int i = tid; i < 832; i += 256){
        int oo = i / 26;
        float a = cbf[oo];
        #pragma unroll
        for (int cg = 0; cg < 8; ++cg) a += part[cg*832 + i];
        cbuf[i] = a > 0.f ? a : 0.f;
    }
    __syncthreads();

    {   // fc1: 832 -> 64, 4 partial groups
        int p = tid >> 6, j = tid & 63;
        float a = 0.f;
        int m0 = p*208;
        #pragma unroll 4
        for (int m = m0; m < m0 + 208; ++m)
            a += cbuf[m] * l1wf[(size_t)m*NH + j];
        part[p*NH + j] = a;
    }
    __syncthreads();
    if (tid < NH){
        float v = part[tid] + part[NH+tid] + part[2*NH+tid] + part[3*NH+tid] + l1bf[tid];
        fbuf[tid] = v > 0.f ? v : 0.f;
    }
    __syncthreads();
    if (tid < NCLS){
        float a = l2bf[tid];
        #pragma unroll
        for (int j = 0; j < NH; ++j) a += fbuf[j] * l2wf[j*NCLS + tid];
        logitsS[tid] = a;
    }
    __syncthreads();
    if (tid == 0){
        float m = logitsS[0];
        for (int c = 1; c < NCLS; ++c) m = fmaxf(m, logitsS[c]);
        float ssum = 0.f;
        for (int c = 0; c < NCLS; ++c) ssum += expf(logitsS[c]-m);
        float lse = m + logf(ssum);
        for (int c = 0; c < NCLS; ++c)
            outp[(size_t)g*NCLS + c] = logitsS[c] - lse;
    }
}

extern "C" void kernel_launch(void* const* d_in, const int* in_sizes, int n_in,
                              void* d_out, int out_size, void* d_ws, size_t ws_size,
                              hipStream_t stream) {
    const void* x    = d_in[0];
    const int*  ei   = (const int*)d_in[1];
    const int*  batch= (const int*)d_in[2];
    const void *W1l=d_in[3], *b1=d_in[4],  *W1r=d_in[5];
    const void *W2l=d_in[6], *b2=d_in[7],  *W2r=d_in[8];
    const void *W3l=d_in[9], *b3=d_in[10], *W3r=d_in[11];
    const void *convw=d_in[12], *convb=d_in[13];
    const void *l1w=d_in[14], *l1b=d_in[15];
    const void *l2w=d_in[16], *l2b=d_in[17];
    float* out = (float*)d_out;

    float* wsf = (float*)d_ws;
    float* A  = wsf;                             // 50000*64
    float* Bb = A  + (size_t)NND*NH;             // 50000*64
    float* C  = Bb + (size_t)NND*NH;             // 50000*64
    int2* bedges = (int2*)(C + (size_t)NND*NH);  // 800000 int2 (8B-aligned: 38.4MB offset)
    float* wT   = (float*)(bedges + NE);         // 10240
    float* cbf  = wT + 10240;                    // 32
    float* l1wf = cbf + 32;                      // 53248
    float* l1bf = l1wf + 53248;                  // 64
    float* l2wf = l1bf + 64;                     // 640
    float* l2bf = l2wf + 640;                    // 10 (+pad)
    int* starts = (int*)(l2bf + 16);             // 513
    int* flags  = starts + 520;                  // 2
    int* bcnt   = flags + 8;                     // 49
    int* bbase  = bcnt + 64;                     // 50
    int* bcur   = bbase + 64;                    // 49
    int* offs   = bcur + 64;                     // 50001
    int* csr    = offs + NND + 3;                // 800000

    probe_kernel<<<1, 256, 0, stream>>>((const unsigned int*)x, ei, flags);
    setup_kernel<<<(53248+255)/256, 256, 0, stream>>>(batch, starts,
                                                      convw, convb, l1w, l1b, l2w, l2b,
                                                      wT, cbf, l1wf, l1bf, l2wf, l2bf, flags);

    // ---- CSR build via bucket sort (once; reused by all 3 layers) ----
    const int NTILE = (NE + 4095)/4096;          // 196
    hipMemsetAsync(bcnt, 0, NBKT*sizeof(int), stream);
    bucket_count<<<NTILE, 256, 0, stream>>>(ei, bcnt, flags);
    bucket_scan<<<1, 64, 0, stream>>>(bcnt, bbase, bcur, offs);
    bucket_scatter<<<NTILE, 256, 0, stream>>>(ei, bcur, bedges, flags);
    csr_finalize<<<NBKT, 1024, 0, stream>>>(bedges, bbase, offs, csr);

    int gblocks = (NND + 15)/16;                 // 3125
    int ngath   = (NND*16 + 255)/256;            // 3125

    // ---- layer 1: x -> B ----
    dualgemm_kernel<NF><<<gblocks,256,0,stream>>>(x, W1l, W1r, b1, A, Bb, flags, 0);
    gather_kernel<<<ngath,256,0,stream>>>((const float4*)A, offs, csr, Bb, Bb);

    // ---- layer 2: B -> C ----
    dualgemm_kernel<NH><<<gblocks,256,0,stream>>>(Bb, W2l, W2r, b2, A, C, flags, 1);
    gather_kernel<<<ngath,256,0,stream>>>((const float4*)A, offs, csr, C, C);

    // ---- layer 3: C -> B ----
    dualgemm_kernel<NH><<<gblocks,256,0,stream>>>(C, W3l, W3r, b3, A, Bb, flags, 1);
    gather_kernel<<<ngath,256,0,stream>>>((const float4*)A, offs, csr, Bb, Bb);

    // ---- head: fused selection + dense tail ----
    head2_kernel<<<NB,256,0,stream>>>(Bb, starts, wT, cbf, l1wf, l1bf, l2wf, l2bf, out);
}